// Round 8
// baseline (308.964 us; speedup 1.0000x reference)
//
#include <hip/hip_runtime.h>

#define NPA   4096
#define DHD   256
#define EDG   131072
#define OS    4104
#define TBL_SZ ((size_t)NPA * DHD)   // elements per table

// ---- ws layout (byte offsets) ----
#define B_AH    ((size_t)0)                       // feats f16: 2 * 1M * 2B = 4 MB
#define B_WH    (B_AH + 2 * TBL_SZ * 2)           // weights f16: 1 MB
#define B_TBL   (B_WH + (size_t)8 * 65536 * 2)    // 8 Wh tables f16 = 16 MB
#define B_SCORE (B_TBL + 8 * TBL_SZ * 2)          // 10 * 4096*4 fp32 (plain stores)
// ---- zeroed region (single memset) ----
#define B_CNT   (B_SCORE + (size_t)10 * NPA * 4 * 4)
#define B_SCD   (B_CNT + (size_t)4 * NPA * 4)
#define B_DEN   (B_SCD + 8 * 4)
#define B_NUM   (B_DEN + 8 * 4)
#define B_TKT   (B_NUM + 512 * 4)
#define B_ZEND  (B_TKT + 16)
// ---- rest ----
#define B_OFFS  (B_ZEND)
#define B_CUR   (B_OFFS + (size_t)4 * OS * 4)
#define B_PERM  (B_CUR + (size_t)4 * NPA * 4)     // dst-sorted src idx: 4*E*4 = 2 MB
#define B_WHIN  (B_PERM + (size_t)4 * EDG * 4)    // 256 fp32

typedef _Float16 half8 __attribute__((ext_vector_type(8)));
typedef _Float16 half4 __attribute__((ext_vector_type(4)));
typedef _Float16 half2v __attribute__((ext_vector_type(2)));
typedef float floatx4 __attribute__((ext_vector_type(4)));

struct CastArgs { const float* src[10]; };
struct GemmArgs {
    const float* b[8];
    const float* att0[8]; const float* att1[8];
    int sj0[8]; int sj1[8];
};
struct EdgeArgs { const int* src[4]; const int* dst[4]; };

__device__ __forceinline__ float lrelu(float x) { return x >= 0.0f ? x : 0.2f * x; }
__device__ __forceinline__ half2v bc2(int v) { return __builtin_bit_cast(half2v, v); }
__device__ __forceinline__ half2v cvt2(float a, float b) {
    return __builtin_bit_cast(half2v, __builtin_amdgcn_cvt_pkrtz(a, b));
}

// per-edge head-softmax attention weight for `head`, from src score row g and dst row ad
__device__ __forceinline__ float attn_head(float4 g, float4 ad, int head) {
    float e0 = __expf(lrelu(g.x + ad.x));
    float e1 = __expf(lrelu(g.y + ad.y));
    float e2 = __expf(lrelu(g.z + ad.z));
    float e3 = __expf(lrelu(g.w + ad.w));
    float sel = (head & 2) ? ((head & 1) ? e3 : e2) : ((head & 1) ? e1 : e0);
    return sel * __builtin_amdgcn_rcpf(e0 + e1 + e2 + e3);
}

// bid<2560: fp32->f16 cast; 2560..2623: Whin+scd; 2624..2815: dst histogram
__global__ __launch_bounds__(256) void prep_kernel(CastArgs ca, EdgeArgs ea,
        const float* __restrict__ fs, const float* __restrict__ Win,
        const float* __restrict__ bin, const float* __restrict__ attP,
        const float* __restrict__ attA, _Float16* __restrict__ dst,
        int* __restrict__ cnt, float* __restrict__ whin, float* __restrict__ scd) {
    int bid = blockIdx.x;
    if (bid < 2560) {
        size_t i4 = ((size_t)bid * 256 + threadIdx.x) * 4;
        const float* s; size_t off;
        if (i4 < TBL_SZ)            { s = ca.src[0]; off = i4; }
        else if (i4 < 2 * TBL_SZ)   { s = ca.src[1]; off = i4 - TBL_SZ; }
        else { size_t r = i4 - 2 * TBL_SZ; s = ca.src[2 + (r >> 16)]; off = r & 65535; }
        float4 v = *(const float4*)(s + off);
        half4 hh = {(_Float16)v.x, (_Float16)v.y, (_Float16)v.z, (_Float16)v.w};
        *(half4*)(dst + i4) = hh;
        return;
    }
    int wave = threadIdx.x >> 6, lane = threadIdx.x & 63;
    if (bid < 2624) {
        int o = (bid - 2560) * 4 + wave;
        float4 w = *(const float4*)&Win[(size_t)o * 256 + lane * 4];
        float4 f = *(const float4*)&fs[lane * 4];
        float v = w.x * f.x + w.y * f.y + w.z * f.z + w.w * f.w;
        for (int d = 32; d; d >>= 1) v += __shfl_xor(v, d);
        if (lane == 0) {
            v += bin[o];
            whin[o] = v;
            atomicAdd(&scd[o >> 6], v * attP[o]);
            atomicAdd(&scd[4 + (o >> 6)], v * attA[o]);
        }
        return;
    }
    int tid = (bid - 2624) * 256 + threadIdx.x;      // 0..49151
    for (int idx = tid; idx < 4 * EDG; idx += 192 * 256) {
        int r = idx >> 17;
        int e = idx & (EDG - 1);
        atomicAdd(&cnt[r * NPA + ea.dst[r][e]], 1);
    }
}

// one block per (job, m-tile): 64 rows x 256 cols; wave w = head w (64-col strip).
__global__ __launch_bounds__(256) void gemm_kernel(const _Float16* __restrict__ Ah,
        const _Float16* __restrict__ Whb, GemmArgs ga,
        _Float16* __restrict__ tblBase, float* __restrict__ score) {
    int j = blockIdx.x >> 6;
    int mt = blockIdx.x & 63;
    int w = threadIdx.x >> 6, lane = threadIdx.x & 63;
    int quad = lane >> 4, l16 = lane & 15;
    const _Float16* A = Ah + (size_t)(j >> 2) * TBL_SZ;
    const _Float16* W = Whb + (size_t)j * 65536;
    const float* bias = ga.b[j];
    _Float16* out = tblBase + (size_t)j * TBL_SZ;
    int mr0 = mt * 64;
    int nc0 = w * 64;
    const _Float16* ap[4];
    const _Float16* bp[4];
#pragma unroll
    for (int g = 0; g < 4; ++g) {
        ap[g] = A + (size_t)(mr0 + g * 16 + l16) * 256 + quad * 8;
        bp[g] = W + (size_t)(nc0 + g * 16 + l16) * 256 + quad * 8;
    }
    floatx4 acc[4][4];
#pragma unroll
    for (int rg = 0; rg < 4; ++rg)
#pragma unroll
        for (int cg = 0; cg < 4; ++cg) acc[rg][cg] = (floatx4){0, 0, 0, 0};
#pragma unroll
    for (int k0 = 0; k0 < 256; k0 += 32) {
        half8 av[4], bv[4];
#pragma unroll
        for (int g = 0; g < 4; ++g) av[g] = *(const half8*)(ap[g] + k0);
#pragma unroll
        for (int g = 0; g < 4; ++g) bv[g] = *(const half8*)(bp[g] + k0);
#pragma unroll
        for (int rg = 0; rg < 4; ++rg)
#pragma unroll
            for (int cg = 0; cg < 4; ++cg)
                acc[rg][cg] = __builtin_amdgcn_mfma_f32_16x16x32_f16(av[rg], bv[cg], acc[rg][cg], 0, 0, 0);
    }
    float bc[4];
#pragma unroll
    for (int cg = 0; cg < 4; ++cg) bc[cg] = bias[nc0 + cg * 16 + l16];
#pragma unroll
    for (int rg = 0; rg < 4; ++rg)
#pragma unroll
        for (int i = 0; i < 4; ++i) {
            int row = mr0 + rg * 16 + quad * 4 + i;
#pragma unroll
            for (int cg = 0; cg < 4; ++cg)
                out[(size_t)row * 256 + nc0 + cg * 16 + l16] = (_Float16)(acc[rg][cg][i] + bc[cg]);
        }
#pragma unroll
    for (int tt = 0; tt < 2; ++tt) {
        const float* att = tt ? ga.att1[j] : ga.att0[j];
        int sj = tt ? ga.sj1[j] : ga.sj0[j];
        if (!att) continue;
        float at[4];
#pragma unroll
        for (int cg = 0; cg < 4; ++cg) at[cg] = att[nc0 + cg * 16 + l16];
        float* sb = score + (size_t)sj * NPA * 4;
#pragma unroll
        for (int rg = 0; rg < 4; ++rg)
#pragma unroll
            for (int i = 0; i < 4; ++i) {
                float p = (acc[rg][0][i] + bc[0]) * at[0] + (acc[rg][1][i] + bc[1]) * at[1]
                        + (acc[rg][2][i] + bc[2]) * at[2] + (acc[rg][3][i] + bc[3]) * at[3];
                p += __shfl_xor(p, 1); p += __shfl_xor(p, 2);
                p += __shfl_xor(p, 4); p += __shfl_xor(p, 8);
                if (l16 == 0) {
                    int row = mr0 + rg * 16 + quad * 4 + i;
                    sb[(size_t)row * 4 + w] = p;
                }
            }
    }
}

// exclusive scan of counts -> offsets + cursor, shfl-based (2 barriers)
__global__ __launch_bounds__(1024) void scan_kernel(const int* __restrict__ counts,
                                                    int* __restrict__ offs, int* __restrict__ cur) {
    int r = blockIdx.x;
    int t = threadIdx.x;
    int wave = t >> 6, lane = t & 63;
    int4 v = *(const int4*)&counts[(size_t)r * NPA + t * 4];
    int lsum = v.x + v.y + v.z + v.w;
    int s = lsum;
#pragma unroll
    for (int d = 1; d < 64; d <<= 1) {
        int u = __shfl_up(s, d);
        if (lane >= d) s += u;
    }
    __shared__ int wsum[16];
    if (lane == 63) wsum[wave] = s;
    __syncthreads();
    if (wave == 0 && lane < 16) {
        int wv = wsum[lane];
#pragma unroll
        for (int d = 1; d < 16; d <<= 1) {
            int u = __shfl_up(wv, d);
            if (lane >= d) wv += u;
        }
        wsum[lane] = wv;
    }
    __syncthreads();
    int base = (wave ? wsum[wave - 1] : 0) + s - lsum;
    int4 ov = {base, base + v.x, base + v.x + v.y, base + v.x + v.y + v.z};
    *(int4*)&offs[(size_t)r * OS + t * 4] = ov;
    *(int4*)&cur[(size_t)r * NPA + t * 4] = ov;
    if (t == 1023) offs[(size_t)r * OS + NPA] = base + lsum;
}

// write src index dst-sorted (4B per edge); 2 edges/thread
__global__ __launch_bounds__(256) void scatter_kernel(EdgeArgs ea, int* __restrict__ cur,
                                                      int* __restrict__ perm) {
    int idx = (blockIdx.x * 256 + threadIdx.x) * 2;
    int r = idx >> 17;
    int e = idx & (EDG - 1);
    int2 s2 = *(const int2*)&ea.src[r][e];
    int2 d2 = *(const int2*)&ea.dst[r][e];
    int p0 = atomicAdd(&cur[r * NPA + d2.x], 1);
    perm[(size_t)r * EDG + p0] = s2.x;
    int p1 = atomicAdd(&cur[r * NPA + d2.y], 1);
    perm[(size_t)r * EDG + p1] = s2.y;
}

// per dst node: out = relu(Wh_skip + sum attn*Wh_src); attn recomputed inline from
// L1-resident score tables; 8 edges in flight per wave (2 half-waves x 4-deep).
__global__ __launch_bounds__(256) void agg_kernel(const int* __restrict__ offs,
        const int* __restrict__ perm, const float* __restrict__ score,
        const _Float16* __restrict__ tblBase, float* __restrict__ outBase) {
    int side = blockIdx.y;
    int wave = threadIdx.x >> 6, lane = threadIdx.x & 63;
    int dn = blockIdx.x * 4 + wave;
    int h = lane >> 5, l32 = lane & 31;
    int head = l32 >> 3;
    half2v accA[4] = {{0,0},{0,0},{0,0},{0,0}};
    half2v accB[4] = {{0,0},{0,0},{0,0},{0,0}};
    const int srcIdx[4] = {1, 2, 5, 6};
#pragma unroll
    for (int q = 0; q < 2; ++q) {
        int r = side + q * 2;
        const int* of = offs + (size_t)r * OS;
        const int* pm = perm + (size_t)r * EDG;
        const float* ss = score + (size_t)r * NPA * 4;
        float4 ad = *(const float4*)&score[(size_t)(4 + r) * NPA * 4 + (size_t)dn * 4];
        const _Float16* wh = tblBase + (size_t)srcIdx[r] * TBL_SZ;
        int beg = of[dn], end = of[dn + 1];
        int i = beg;
        int s0 = (i + h     < end) ? pm[i + h]     : 0;
        int s1 = (i + 2 + h < end) ? pm[i + 2 + h] : 0;
        int s2 = (i + 4 + h < end) ? pm[i + 4 + h] : 0;
        int s3 = (i + 6 + h < end) ? pm[i + 6 + h] : 0;
        while (i < end) {
            int ni = i + 8;
            float4 g0 = *(const float4*)&ss[(size_t)s0 * 4];
            float4 g1 = *(const float4*)&ss[(size_t)s1 * 4];
            float4 g2 = *(const float4*)&ss[(size_t)s2 * 4];
            float4 g3 = *(const float4*)&ss[(size_t)s3 * 4];
            half8 w0 = *(const half8*)(wh + (size_t)s0 * 256 + l32 * 8);
            half8 w1 = *(const half8*)(wh + (size_t)s1 * 256 + l32 * 8);
            half8 w2 = *(const half8*)(wh + (size_t)s2 * 256 + l32 * 8);
            half8 w3 = *(const half8*)(wh + (size_t)s3 * 256 + l32 * 8);
            int t0 = (ni + h     < end) ? pm[ni + h]     : 0;
            int t1 = (ni + 2 + h < end) ? pm[ni + 2 + h] : 0;
            int t2 = (ni + 4 + h < end) ? pm[ni + 4 + h] : 0;
            int t3 = (ni + 6 + h < end) ? pm[ni + 6 + h] : 0;
            float a0 = (i + h     < end) ? attn_head(g0, ad, head) : 0.f;
            float a1 = (i + 2 + h < end) ? attn_head(g1, ad, head) : 0.f;
            float a2 = (i + 4 + h < end) ? attn_head(g2, ad, head) : 0.f;
            float a3 = (i + 6 + h < end) ? attn_head(g3, ad, head) : 0.f;
            half2v ha0 = cvt2(a0, a0), ha1 = cvt2(a1, a1);
            half2v ha2 = cvt2(a2, a2), ha3 = cvt2(a3, a3);
            int4 i0 = __builtin_bit_cast(int4, w0);
            int4 i1 = __builtin_bit_cast(int4, w1);
            int4 i2 = __builtin_bit_cast(int4, w2);
            int4 i3 = __builtin_bit_cast(int4, w3);
            accA[0] += bc2(i0.x) * ha0; accA[1] += bc2(i0.y) * ha0;
            accA[2] += bc2(i0.z) * ha0; accA[3] += bc2(i0.w) * ha0;
            accB[0] += bc2(i1.x) * ha1; accB[1] += bc2(i1.y) * ha1;
            accB[2] += bc2(i1.z) * ha1; accB[3] += bc2(i1.w) * ha1;
            accA[0] += bc2(i2.x) * ha2; accA[1] += bc2(i2.y) * ha2;
            accA[2] += bc2(i2.z) * ha2; accA[3] += bc2(i2.w) * ha2;
            accB[0] += bc2(i3.x) * ha3; accB[1] += bc2(i3.y) * ha3;
            accB[2] += bc2(i3.z) * ha3; accB[3] += bc2(i3.w) * ha3;
            s0 = t0; s1 = t1; s2 = t2; s3 = t3;
            i = ni;
        }
    }
    float f[8];
#pragma unroll
    for (int k = 0; k < 4; ++k) {
        half2v s = accA[k] + accB[k];
        f[2 * k] = (float)s[0];
        f[2 * k + 1] = (float)s[1];
    }
#pragma unroll
    for (int k = 0; k < 8; ++k) f[k] += __shfl_xor(f[k], 32);
    if (h == 0) {
        const _Float16* skip = tblBase + (size_t)(side * 4) * TBL_SZ + (size_t)dn * 256 + l32 * 8;
        half8 sv = *(const half8*)skip;
        float* op = outBase + ((size_t)side * NPA + dn) * 256 + l32 * 8;
        float4 o0 = {fmaxf(f[0] + (float)sv[0], 0.f), fmaxf(f[1] + (float)sv[1], 0.f),
                     fmaxf(f[2] + (float)sv[2], 0.f), fmaxf(f[3] + (float)sv[3], 0.f)};
        float4 o1 = {fmaxf(f[4] + (float)sv[4], 0.f), fmaxf(f[5] + (float)sv[5], 0.f),
                     fmaxf(f[6] + (float)sv[6], 0.f), fmaxf(f[7] + (float)sv[7], 0.f)};
        *(float4*)op = o0;
        *(float4*)(op + 4) = o1;
    }
}

// state relations p2s (tbl3) / a2s (tbl7) + fused final via last-block ticket
__global__ __launch_bounds__(256) void state_kernel(const _Float16* __restrict__ tblBase,
        const float* __restrict__ score, const float* __restrict__ scd,
        float* __restrict__ den, float* __restrict__ num,
        const float* __restrict__ whin, float* __restrict__ out, int* __restrict__ ticket) {
    int r = blockIdx.y;
    int blk = blockIdx.x;                       // 0..127
    int t = threadIdx.x;
    int h = t >> 6;
    const _Float16* wh = tblBase + (size_t)(r == 0 ? 3 : 7) * TBL_SZ;
    const float* as = score + (size_t)(8 + r) * NPA * 4;
    float dh = scd[r * 4 + h];
    float dsum = 0.0f, acc = 0.0f;
    for (int i = blk; i < NPA; i += 128) {
        float x = lrelu(as[(size_t)i * 4 + h] + dh);
        float w = __expf(x);
        dsum += w;
        acc += w * (float)wh[(size_t)i * 256 + t];
    }
    atomicAdd(&num[r * 256 + t], acc);
    if ((t & 63) == 0) atomicAdd(&den[r * 4 + h], dsum);
    __threadfence();
    __shared__ int last;
    if (t == 0) last = (atomicAdd(ticket, 1) == 255);
    __syncthreads();
    if (last) {
        // cross-block reads via atomics (memory-side coherent across XCDs)
        float n0 = atomicAdd(&num[t], 0.f);
        float n1 = atomicAdd(&num[256 + t], 0.f);
        float d0 = atomicAdd(&den[h], 0.f);
        float d1 = atomicAdd(&den[4 + h], 0.f);
        float v = whin[t] + n0 / d0 + n1 / d1;
        out[t] = fmaxf(v, 0.f);
    }
}

extern "C" void kernel_launch(void* const* d_in, const int* in_sizes, int n_in,
                              void* d_out, int out_size, void* d_ws, size_t ws_size,
                              hipStream_t stream) {
    auto F = [&](int i) { return (const float*)d_in[i]; };
    char* ws = (char*)d_ws;
    _Float16* Ah  = (_Float16*)(ws + B_AH);
    _Float16* Whb = (_Float16*)(ws + B_WH);
    _Float16* tbl = (_Float16*)(ws + B_TBL);
    float* score  = (float*)(ws + B_SCORE);
    int* cnt      = (int*)(ws + B_CNT);
    float* scd    = (float*)(ws + B_SCD);
    float* den    = (float*)(ws + B_DEN);
    float* num    = (float*)(ws + B_NUM);
    int* ticket   = (int*)(ws + B_TKT);
    int* offs     = (int*)(ws + B_OFFS);
    int* cur      = (int*)(ws + B_CUR);
    int* perm     = (int*)(ws + B_PERM);
    float* whin   = (float*)(ws + B_WHIN);

    (void)hipMemsetAsync(ws + B_CNT, 0, B_ZEND - B_CNT, stream);

    CastArgs ca = {{F(0), F(1), F(3), F(7), F(9), F(15), F(5), F(11), F(13), F(17)}};
    EdgeArgs ea = {{(const int*)d_in[33], (const int*)d_in[35], (const int*)d_in[37], (const int*)d_in[39]},
                   {(const int*)d_in[34], (const int*)d_in[36], (const int*)d_in[38], (const int*)d_in[40]}};

    prep_kernel<<<2816, 256, 0, stream>>>(ca, ea, F(2), F(19), F(20), F(30), F(32),
                                          Ah, cnt, whin, scd);

    GemmArgs ga;
    const int bIdx[8] = {4, 8, 10, 16, 6, 12, 14, 18};
    for (int j = 0; j < 8; ++j) ga.b[j] = F(bIdx[j]);
    const int a0Idx[8]  = {22, 21, 23, 29, 24, 25, 27, 31};
    const int sj0Arr[8] = { 4,  0,  1,  8,  5,  2,  3,  9};
    for (int j = 0; j < 8; ++j) {
        ga.att0[j] = F(a0Idx[j]); ga.sj0[j] = sj0Arr[j];
        ga.att1[j] = nullptr;     ga.sj1[j] = -1;
    }
    ga.att1[0] = F(26); ga.sj1[0] = 6;   // tbl0: a2p_dst
    ga.att1[4] = F(28); ga.sj1[4] = 7;   // tbl4: a2a_dst

    gemm_kernel<<<512, 256, 0, stream>>>(Ah, Whb, ga, tbl, score);
    scan_kernel<<<4, 1024, 0, stream>>>(cnt, offs, cur);
    scatter_kernel<<<1024, 256, 0, stream>>>(ea, cur, perm);
    agg_kernel<<<dim3(1024, 2), 256, 0, stream>>>(offs, perm, score, tbl, (float*)d_out);
    state_kernel<<<dim3(128, 2), 256, 0, stream>>>(tbl, score, scd, den, num, whin,
                                                   (float*)d_out + 2 * TBL_SZ, ticket);
}

// Round 9
// 269.646 us; speedup vs baseline: 1.1458x; 1.1458x over previous
//
#include <hip/hip_runtime.h>

#define NPA   4096
#define DHD   256
#define EDG   131072
#define OS    4104
#define TBL_SZ ((size_t)NPA * DHD)   // elements per table

// ---- ws layout (byte offsets) ----
#define B_AH    ((size_t)0)                       // feats f16: 4 MB
#define B_WH    (B_AH + 2 * TBL_SZ * 2)           // weights f16: 1 MB
#define B_TBL   (B_WH + (size_t)8 * 65536 * 2)    // 8 Wh tables f16 = 16 MB
#define B_SCORE (B_TBL + 8 * TBL_SZ * 2)          // 10 * 4096*4 fp32 (plain stores)
// ---- zeroed region (single memset) ----
#define B_CNT   (B_SCORE + (size_t)10 * NPA * 4 * 4)
#define B_SCD   (B_CNT + (size_t)4 * NPA * 4)
#define B_DEN   (B_SCD + 8 * 4)
#define B_NUM   (B_DEN + 8 * 4)
#define B_ZEND  (B_NUM + 512 * 4)
// ---- rest ----
#define B_OFFS  (B_ZEND)
#define B_CUR   (B_OFFS + (size_t)4 * OS * 4)
#define B_PKT   (B_CUR + (size_t)4 * NPA * 4)     // dst-sorted {src, attn f16x4}: 8 MB
#define B_WHIN  (B_PKT + (size_t)4 * EDG * 16)    // 256 fp32

typedef _Float16 half8 __attribute__((ext_vector_type(8)));
typedef _Float16 half4 __attribute__((ext_vector_type(4)));
typedef _Float16 half2v __attribute__((ext_vector_type(2)));
typedef float floatx4 __attribute__((ext_vector_type(4)));

struct CastArgs { const float* src[10]; };
struct GemmArgs {
    const float* b[8];
    const float* att0[8]; const float* att1[8];
    int sj0[8]; int sj1[8];
};
struct EdgeArgs { const int* src[4]; const int* dst[4]; };

__device__ __forceinline__ float lrelu(float x) { return x >= 0.0f ? x : 0.2f * x; }

__device__ __forceinline__ int pack2(float a, float b) {
    half2v h = {(_Float16)a, (_Float16)b};
    return __builtin_bit_cast(int, h);
}
__device__ __forceinline__ half2v bc2(int v) { return __builtin_bit_cast(half2v, v); }

// splat the f16 attn coeff for `head` from a packet into both halves of a half2
__device__ __forceinline__ half2v asplat(const int4& p, int head) {
    int w = (head & 2) ? p.z : p.y;
    int b = (head & 1) ? ((w >> 16) & 0xffff) : (w & 0xffff);
    return bc2(b | (b << 16));
}

// bid<32: LDS dst-histogram (8 blocks/relation, first so they overlap the cast);
// 32..95: Whin+scd; 96+: fp32->f16 cast (2560 blocks)
__global__ __launch_bounds__(256) void prep_kernel(CastArgs ca, EdgeArgs ea,
        const float* __restrict__ fs, const float* __restrict__ Win,
        const float* __restrict__ bin, const float* __restrict__ attP,
        const float* __restrict__ attA, _Float16* __restrict__ dst,
        int* __restrict__ cnt, float* __restrict__ whin, float* __restrict__ scd) {
    __shared__ int hist[NPA];
    int bid = blockIdx.x;
    int tid = threadIdx.x;
    if (bid < 32) {
        int r = bid >> 3;
        int chunk = bid & 7;                   // 8 chunks of 16384 edges
        const int* dp = ea.dst[r] + chunk * 16384;
#pragma unroll
        for (int i = 0; i < 16; ++i) hist[tid + i * 256] = 0;
        __syncthreads();
#pragma unroll
        for (int k = 0; k < 64; ++k)
            atomicAdd(&hist[dp[k * 256 + tid]], 1);
        __syncthreads();
        int* cr = cnt + r * NPA;
#pragma unroll
        for (int i = 0; i < 16; ++i) {
            int v = hist[tid + i * 256];
            if (v) atomicAdd(&cr[tid + i * 256], v);
        }
        return;
    }
    int wave = tid >> 6, lane = tid & 63;
    if (bid < 96) {
        int o = (bid - 32) * 4 + wave;
        float4 w = *(const float4*)&Win[(size_t)o * 256 + lane * 4];
        float4 f = *(const float4*)&fs[lane * 4];
        float v = w.x * f.x + w.y * f.y + w.z * f.z + w.w * f.w;
        for (int d = 32; d; d >>= 1) v += __shfl_xor(v, d);
        if (lane == 0) {
            v += bin[o];
            whin[o] = v;
            atomicAdd(&scd[o >> 6], v * attP[o]);
            atomicAdd(&scd[4 + (o >> 6)], v * attA[o]);
        }
        return;
    }
    size_t i4 = ((size_t)(bid - 96) * 256 + tid) * 4;
    const float* s; size_t off;
    if (i4 < TBL_SZ)            { s = ca.src[0]; off = i4; }
    else if (i4 < 2 * TBL_SZ)   { s = ca.src[1]; off = i4 - TBL_SZ; }
    else { size_t r = i4 - 2 * TBL_SZ; s = ca.src[2 + (r >> 16)]; off = r & 65535; }
    float4 v = *(const float4*)(s + off);
    half4 hh = {(_Float16)v.x, (_Float16)v.y, (_Float16)v.z, (_Float16)v.w};
    *(half4*)(dst + i4) = hh;
}

// one block per (job, m-tile): 64 rows x 256 cols; wave w = head w (64-col strip).
__global__ __launch_bounds__(256) void gemm_kernel(const _Float16* __restrict__ Ah,
        const _Float16* __restrict__ Whb, GemmArgs ga,
        _Float16* __restrict__ tblBase, float* __restrict__ score) {
    int j = blockIdx.x >> 6;
    int mt = blockIdx.x & 63;
    int w = threadIdx.x >> 6, lane = threadIdx.x & 63;
    int quad = lane >> 4, l16 = lane & 15;
    const _Float16* A = Ah + (size_t)(j >> 2) * TBL_SZ;
    const _Float16* W = Whb + (size_t)j * 65536;
    const float* bias = ga.b[j];
    _Float16* out = tblBase + (size_t)j * TBL_SZ;
    int mr0 = mt * 64;
    int nc0 = w * 64;
    const _Float16* ap[4];
    const _Float16* bp[4];
#pragma unroll
    for (int g = 0; g < 4; ++g) {
        ap[g] = A + (size_t)(mr0 + g * 16 + l16) * 256 + quad * 8;
        bp[g] = W + (size_t)(nc0 + g * 16 + l16) * 256 + quad * 8;
    }
    floatx4 acc[4][4];
#pragma unroll
    for (int rg = 0; rg < 4; ++rg)
#pragma unroll
        for (int cg = 0; cg < 4; ++cg) acc[rg][cg] = (floatx4){0, 0, 0, 0};
#pragma unroll
    for (int k0 = 0; k0 < 256; k0 += 32) {
        half8 av[4], bv[4];
#pragma unroll
        for (int g = 0; g < 4; ++g) av[g] = *(const half8*)(ap[g] + k0);
#pragma unroll
        for (int g = 0; g < 4; ++g) bv[g] = *(const half8*)(bp[g] + k0);
#pragma unroll
        for (int rg = 0; rg < 4; ++rg)
#pragma unroll
            for (int cg = 0; cg < 4; ++cg)
                acc[rg][cg] = __builtin_amdgcn_mfma_f32_16x16x32_f16(av[rg], bv[cg], acc[rg][cg], 0, 0, 0);
    }
    float bc[4];
#pragma unroll
    for (int cg = 0; cg < 4; ++cg) bc[cg] = bias[nc0 + cg * 16 + l16];
#pragma unroll
    for (int rg = 0; rg < 4; ++rg)
#pragma unroll
        for (int i = 0; i < 4; ++i) {
            int row = mr0 + rg * 16 + quad * 4 + i;
#pragma unroll
            for (int cg = 0; cg < 4; ++cg)
                out[(size_t)row * 256 + nc0 + cg * 16 + l16] = (_Float16)(acc[rg][cg][i] + bc[cg]);
        }
#pragma unroll
    for (int tt = 0; tt < 2; ++tt) {
        const float* att = tt ? ga.att1[j] : ga.att0[j];
        int sj = tt ? ga.sj1[j] : ga.sj0[j];
        if (!att) continue;
        float at[4];
#pragma unroll
        for (int cg = 0; cg < 4; ++cg) at[cg] = att[nc0 + cg * 16 + l16];
        float* sb = score + (size_t)sj * NPA * 4;
#pragma unroll
        for (int rg = 0; rg < 4; ++rg)
#pragma unroll
            for (int i = 0; i < 4; ++i) {
                float p = (acc[rg][0][i] + bc[0]) * at[0] + (acc[rg][1][i] + bc[1]) * at[1]
                        + (acc[rg][2][i] + bc[2]) * at[2] + (acc[rg][3][i] + bc[3]) * at[3];
                p += __shfl_xor(p, 1); p += __shfl_xor(p, 2);
                p += __shfl_xor(p, 4); p += __shfl_xor(p, 8);
                if (l16 == 0) {
                    int row = mr0 + rg * 16 + quad * 4 + i;
                    sb[(size_t)row * 4 + w] = p;
                }
            }
    }
}

// exclusive scan of counts -> offsets + cursor, shfl-based (2 barriers)
__global__ __launch_bounds__(1024) void scan_kernel(const int* __restrict__ counts,
                                                    int* __restrict__ offs, int* __restrict__ cur) {
    int r = blockIdx.x;
    int t = threadIdx.x;
    int wave = t >> 6, lane = t & 63;
    int4 v = *(const int4*)&counts[(size_t)r * NPA + t * 4];
    int lsum = v.x + v.y + v.z + v.w;
    int s = lsum;
#pragma unroll
    for (int d = 1; d < 64; d <<= 1) {
        int u = __shfl_up(s, d);
        if (lane >= d) s += u;
    }
    __shared__ int wsum[16];
    if (lane == 63) wsum[wave] = s;
    __syncthreads();
    if (wave == 0 && lane < 16) {
        int wv = wsum[lane];
#pragma unroll
        for (int d = 1; d < 16; d <<= 1) {
            int u = __shfl_up(wv, d);
            if (lane >= d) wv += u;
        }
        wsum[lane] = wv;
    }
    __syncthreads();
    int base = (wave ? wsum[wave - 1] : 0) + s - lsum;
    int4 ov = {base, base + v.x, base + v.x + v.y, base + v.x + v.y + v.z};
    *(int4*)&offs[(size_t)r * OS + t * 4] = ov;
    *(int4*)&cur[(size_t)r * NPA + t * 4] = ov;
    if (t == 1023) offs[(size_t)r * OS + NPA] = base + lsum;
}

// per-edge head-softmax attn, packed {src, a01, a23, 0}, written dst-sorted; 2 edges/thread
__global__ __launch_bounds__(256) void scatter_attn(EdgeArgs ea, const float* __restrict__ scoreBase,
        int* __restrict__ cur, int4* __restrict__ pkt) {
    int idx = (blockIdx.x * 256 + threadIdx.x) * 2;
    int r = idx >> 17;
    int e = idx & (EDG - 1);
    int2 s2 = *(const int2*)&ea.src[r][e];
    int2 d2 = *(const int2*)&ea.dst[r][e];
    const float* as = scoreBase + (size_t)r * NPA * 4;
    const float* ad = scoreBase + (size_t)(4 + r) * NPA * 4;
    float4 av0 = *(const float4*)&as[(size_t)s2.x * 4];
    float4 dv0 = *(const float4*)&ad[(size_t)d2.x * 4];
    float4 av1 = *(const float4*)&as[(size_t)s2.y * 4];
    float4 dv1 = *(const float4*)&ad[(size_t)d2.y * 4];
#pragma unroll
    for (int u = 0; u < 2; ++u) {
        float4 av = u ? av1 : av0;
        float4 dv = u ? dv1 : dv0;
        int s = u ? s2.y : s2.x;
        int d = u ? d2.y : d2.x;
        float x0 = lrelu(av.x + dv.x), x1 = lrelu(av.y + dv.y);
        float x2 = lrelu(av.z + dv.z), x3 = lrelu(av.w + dv.w);
        float m = fmaxf(fmaxf(x0, x1), fmaxf(x2, x3));
        float e0 = __expf(x0 - m), e1 = __expf(x1 - m), e2 = __expf(x2 - m), e3 = __expf(x3 - m);
        float inv = 1.0f / (e0 + e1 + e2 + e3);
        int pos = atomicAdd(&cur[r * NPA + d], 1);
        int4 pk = {s, pack2(e0 * inv, e1 * inv), pack2(e2 * inv, e3 * inv), 0};
        pkt[(size_t)r * EDG + pos] = pk;
    }
}

// per dst node: out = relu(Wh_skip + sum attn*Wh_src); 8 edges in flight/wave, pk_fma
__global__ __launch_bounds__(256) void agg_kernel(const int* __restrict__ offs,
        const int4* __restrict__ pkt, const _Float16* __restrict__ tblBase,
        float* __restrict__ outBase) {
    int side = blockIdx.y;
    int wave = threadIdx.x >> 6, lane = threadIdx.x & 63;
    int dn = blockIdx.x * 4 + wave;
    int h = lane >> 5, l32 = lane & 31;
    int head = l32 >> 3;
    half2v accA[4] = {{0,0},{0,0},{0,0},{0,0}};
    half2v accB[4] = {{0,0},{0,0},{0,0},{0,0}};
    const int srcIdx[4] = {1, 2, 5, 6};
    const int4 z = {0, 0, 0, 0};
#pragma unroll
    for (int q = 0; q < 2; ++q) {
        int r = side + q * 2;
        const int* of = offs + (size_t)r * OS;
        const int4* pkb = pkt + (size_t)r * EDG;
        const _Float16* wh = tblBase + (size_t)srcIdx[r] * TBL_SZ;
        int beg = of[dn], end = of[dn + 1];
        int i = beg;
        int4 p0 = (i + h     < end) ? pkb[i + h]     : z;
        int4 p1 = (i + 2 + h < end) ? pkb[i + 2 + h] : z;
        int4 p2 = (i + 4 + h < end) ? pkb[i + 4 + h] : z;
        int4 p3 = (i + 6 + h < end) ? pkb[i + 6 + h] : z;
        while (i < end) {
            int ni = i + 8;
            half8 w0 = *(const half8*)(wh + (size_t)p0.x * 256 + l32 * 8);
            half8 w1 = *(const half8*)(wh + (size_t)p1.x * 256 + l32 * 8);
            half8 w2 = *(const half8*)(wh + (size_t)p2.x * 256 + l32 * 8);
            half8 w3 = *(const half8*)(wh + (size_t)p3.x * 256 + l32 * 8);
            int4 n0 = (ni + h     < end) ? pkb[ni + h]     : z;
            int4 n1 = (ni + 2 + h < end) ? pkb[ni + 2 + h] : z;
            int4 n2 = (ni + 4 + h < end) ? pkb[ni + 4 + h] : z;
            int4 n3 = (ni + 6 + h < end) ? pkb[ni + 6 + h] : z;
            half2v a0 = asplat(p0, head), a1 = asplat(p1, head);
            half2v a2 = asplat(p2, head), a3 = asplat(p3, head);
            int4 i0 = __builtin_bit_cast(int4, w0);
            int4 i1 = __builtin_bit_cast(int4, w1);
            int4 i2 = __builtin_bit_cast(int4, w2);
            int4 i3 = __builtin_bit_cast(int4, w3);
            accA[0] += bc2(i0.x) * a0; accA[1] += bc2(i0.y) * a0;
            accA[2] += bc2(i0.z) * a0; accA[3] += bc2(i0.w) * a0;
            accB[0] += bc2(i1.x) * a1; accB[1] += bc2(i1.y) * a1;
            accB[2] += bc2(i1.z) * a1; accB[3] += bc2(i1.w) * a1;
            accA[0] += bc2(i2.x) * a2; accA[1] += bc2(i2.y) * a2;
            accA[2] += bc2(i2.z) * a2; accA[3] += bc2(i2.w) * a2;
            accB[0] += bc2(i3.x) * a3; accB[1] += bc2(i3.y) * a3;
            accB[2] += bc2(i3.z) * a3; accB[3] += bc2(i3.w) * a3;
            p0 = n0; p1 = n1; p2 = n2; p3 = n3;
            i = ni;
        }
    }
    float f[8];
#pragma unroll
    for (int k = 0; k < 4; ++k) {
        half2v s = accA[k] + accB[k];
        f[2 * k] = (float)s[0];
        f[2 * k + 1] = (float)s[1];
    }
#pragma unroll
    for (int k = 0; k < 8; ++k) f[k] += __shfl_xor(f[k], 32);
    if (h == 0) {
        const _Float16* skip = tblBase + (size_t)(side * 4) * TBL_SZ + (size_t)dn * 256 + l32 * 8;
        half8 sv = *(const half8*)skip;
        float* op = outBase + ((size_t)side * NPA + dn) * 256 + l32 * 8;
        float4 o0 = {fmaxf(f[0] + (float)sv[0], 0.f), fmaxf(f[1] + (float)sv[1], 0.f),
                     fmaxf(f[2] + (float)sv[2], 0.f), fmaxf(f[3] + (float)sv[3], 0.f)};
        float4 o1 = {fmaxf(f[4] + (float)sv[4], 0.f), fmaxf(f[5] + (float)sv[5], 0.f),
                     fmaxf(f[6] + (float)sv[6], 0.f), fmaxf(f[7] + (float)sv[7], 0.f)};
        *(float4*)op = o0;
        *(float4*)(op + 4) = o1;
    }
}

// state relations p2s (tbl3) / a2s (tbl7): softmax over 4096 nodes
__global__ __launch_bounds__(256) void state_kernel(const _Float16* __restrict__ tblBase,
        const float* __restrict__ scoreBase, const float* __restrict__ scd,
        float* __restrict__ den, float* __restrict__ num) {
    int r = blockIdx.y;
    int blk = blockIdx.x;                       // 0..127
    int t = threadIdx.x;
    int h = t >> 6;
    const _Float16* wh = tblBase + (size_t)(r == 0 ? 3 : 7) * TBL_SZ;
    const float* as = scoreBase + (size_t)(8 + r) * NPA * 4;
    float dh = scd[r * 4 + h];
    float dsum = 0.0f, acc = 0.0f;
    for (int i = blk; i < NPA; i += 128) {
        float x = lrelu(as[(size_t)i * 4 + h] + dh);
        float w = __expf(x);
        dsum += w;
        acc += w * (float)wh[(size_t)i * 256 + t];
    }
    atomicAdd(&num[r * 256 + t], acc);
    if ((t & 63) == 0) atomicAdd(&den[r * 4 + h], dsum);
}

__global__ __launch_bounds__(256) void state_final(const float* __restrict__ whin,
        const float* __restrict__ den, const float* __restrict__ num, float* __restrict__ out) {
    int t = threadIdx.x;
    int h = t >> 6;
    float v = whin[t] + num[t] / den[h] + num[256 + t] / den[4 + h];
    out[t] = v > 0.0f ? v : 0.0f;
}

extern "C" void kernel_launch(void* const* d_in, const int* in_sizes, int n_in,
                              void* d_out, int out_size, void* d_ws, size_t ws_size,
                              hipStream_t stream) {
    auto F = [&](int i) { return (const float*)d_in[i]; };
    char* ws = (char*)d_ws;
    _Float16* Ah  = (_Float16*)(ws + B_AH);
    _Float16* Whb = (_Float16*)(ws + B_WH);
    _Float16* tbl = (_Float16*)(ws + B_TBL);
    float* score  = (float*)(ws + B_SCORE);
    int* cnt      = (int*)(ws + B_CNT);
    float* scd    = (float*)(ws + B_SCD);
    float* den    = (float*)(ws + B_DEN);
    float* num    = (float*)(ws + B_NUM);
    int* offs     = (int*)(ws + B_OFFS);
    int* cur      = (int*)(ws + B_CUR);
    int4* pkt     = (int4*)(ws + B_PKT);
    float* whin   = (float*)(ws + B_WHIN);

    (void)hipMemsetAsync(ws + B_CNT, 0, B_ZEND - B_CNT, stream);

    CastArgs ca = {{F(0), F(1), F(3), F(7), F(9), F(15), F(5), F(11), F(13), F(17)}};
    EdgeArgs ea = {{(const int*)d_in[33], (const int*)d_in[35], (const int*)d_in[37], (const int*)d_in[39]},
                   {(const int*)d_in[34], (const int*)d_in[36], (const int*)d_in[38], (const int*)d_in[40]}};

    prep_kernel<<<2656, 256, 0, stream>>>(ca, ea, F(2), F(19), F(20), F(30), F(32),
                                          Ah, cnt, whin, scd);

    GemmArgs ga;
    const int bIdx[8] = {4, 8, 10, 16, 6, 12, 14, 18};
    for (int j = 0; j < 8; ++j) ga.b[j] = F(bIdx[j]);
    const int a0Idx[8]  = {22, 21, 23, 29, 24, 25, 27, 31};
    const int sj0Arr[8] = { 4,  0,  1,  8,  5,  2,  3,  9};
    for (int j = 0; j < 8; ++j) {
        ga.att0[j] = F(a0Idx[j]); ga.sj0[j] = sj0Arr[j];
        ga.att1[j] = nullptr;     ga.sj1[j] = -1;
    }
    ga.att1[0] = F(26); ga.sj1[0] = 6;   // tbl0: a2p_dst
    ga.att1[4] = F(28); ga.sj1[4] = 7;   // tbl4: a2a_dst

    gemm_kernel<<<512, 256, 0, stream>>>(Ah, Whb, ga, tbl, score);
    scan_kernel<<<4, 1024, 0, stream>>>(cnt, offs, cur);
    scatter_attn<<<1024, 256, 0, stream>>>(ea, score, cur, pkt);
    agg_kernel<<<dim3(1024, 2), 256, 0, stream>>>(offs, pkt, tbl, (float*)d_out);
    state_kernel<<<dim3(128, 2), 256, 0, stream>>>(tbl, score, scd, den, num);
    state_final<<<1, 256, 0, stream>>>(whin, den, num, (float*)d_out + 2 * TBL_SZ);
}